// Round 1
// 951.361 us; speedup vs baseline: 1.2365x; 1.2365x over previous
//
#include <hip/hip_runtime.h>

#define BB 8
#define LL 2048
#define DD 512
#define QQ 8
#define KK 2048
#define MM (BB*LL)      // 16384 points

#define BMt 128         // block tile M (2 wr-waves x 64)
#define BNt 128         // block tile N (2 wc-waves x 64)
#define NSTEPS 16       // DD/32
#define NTILES (KK/BNt) // 16
#define MTILES (MM/BMt) // 128

typedef __attribute__((ext_vector_type(8))) short short8;
typedef __attribute__((ext_vector_type(4))) float f32x4;

#define GLDS(src, dst) __builtin_amdgcn_global_load_lds( \
    (const __attribute__((address_space(1))) void*)(src), \
    (__attribute__((address_space(3))) void*)(dst), 16, 0, 0)

__device__ __forceinline__ ushort f2bf(float f) {
    uint u = __float_as_uint(f);
    u += 0x7FFFu + ((u >> 16) & 1u);
    return (ushort)(u >> 16);
}

// ---------------- cb2: fp32 squared norms ----------------
__global__ __launch_bounds__(256) void cb2_kernel(const float* __restrict__ cb,
                                                  float* __restrict__ cb2) {
    int row  = blockIdx.x * 4 + (threadIdx.x >> 6);
    int lane = threadIdx.x & 63;
    const float* r = cb + (size_t)row * DD + lane * 8;
    float4 a = *(const float4*)r;
    float4 b = *(const float4*)(r + 4);
    float s = a.x*a.x + a.y*a.y + a.z*a.z + a.w*a.w
            + b.x*b.x + b.y*b.y + b.z*b.z + b.w*b.w;
    #pragma unroll
    for (int off = 32; off >= 1; off >>= 1) s += __shfl_xor(s, off);
    if (lane == 0) cb2[row] = s;
}

// ---------------- codebook hi-part, wave-contiguous frag order ----------------
// frag idx = (nt*16+ks)*512 + colblk*64 + kk*16 + colr   (nt: 16 tiles of 128 cols)
__global__ __launch_bounds__(256) void bprep_kernel(const float* __restrict__ cbq,
                                                    short8* __restrict__ bh) {
    int r = blockIdx.x * 256 + threadIdx.x;   // 0..131071, write-coalesced
    int colr   = r & 15;
    int kk     = (r >> 4) & 3;
    int colblk = (r >> 6) & 7;
    int ks     = (r >> 9) & 15;
    int nt     = r >> 13;
    const float* src = cbq + (size_t)(nt * 128 + colblk * 16 + colr) * DD + ks * 32 + kk * 8;
    float f[8];
    *(float4*)&f[0] = *(const float4*)src;
    *(float4*)&f[4] = *(const float4*)(src + 4);
    short8 h8;
    #pragma unroll
    for (int j = 0; j < 8; j++) h8[j] = (short)f2bf(f[j]);
    bh[r] = h8;
}

// A frag index for point row, lane (lane covers d = lane*8): 128-row tiles
__device__ __forceinline__ size_t a_frag_idx(int row, int lane) {
    int mt = row >> 7, rowblk = (row >> 4) & 7, rowr = row & 15;
    int ks = lane >> 2, kk = lane & 3;
    return ((size_t)(mt * 16 + ks)) * 512 + rowblk * 64 + kk * 16 + rowr;
}

// ---------------- level-0 A prep: resid <- x, ah <- bf16(x) frags ----------------
__global__ __launch_bounds__(256) void aprep0_kernel(const float* __restrict__ x,
                                                     float* __restrict__ resid,
                                                     short8* __restrict__ ah) {
    const int wid  = threadIdx.x >> 6;
    const int lane = threadIdx.x & 63;
    const int row  = blockIdx.x * 4 + wid;
    const float* src = x + (size_t)row * DD + lane * 8;
    float4 v0 = *(const float4*)src;
    float4 v1 = *(const float4*)(src + 4);
    float* dst = resid + (size_t)row * DD + lane * 8;
    *(float4*)dst       = v0;
    *(float4*)(dst + 4) = v1;
    short8 h;
    h[0] = (short)f2bf(v0.x); h[1] = (short)f2bf(v0.y);
    h[2] = (short)f2bf(v0.z); h[3] = (short)f2bf(v0.w);
    h[4] = (short)f2bf(v1.x); h[5] = (short)f2bf(v1.y);
    h[6] = (short)f2bf(v1.z); h[7] = (short)f2bf(v1.w);
    ah[a_frag_idx(row, lane)] = h;
}

// ---------------- 1-term bf16 GEMM + per-tile (v1,i1,v2) ----------------
// 2048 blocks x 256 thr; XCD-chunked remap; 4 waves (2x2), wave tile 64x64.
// MFMA operands SWAPPED (acc = mfma(bf, af)): C/D layout then gives each lane
// 16 cols of ONE point row per m-frag -> in-register top-2 scan, only 2 shfl
// stages (l4 merge) instead of 16x 4-stage column reductions.
__global__ __launch_bounds__(256, 4) void gemm_argmin_kernel(
    const short8* __restrict__ ah,
    const short8* __restrict__ bh,
    const float*  __restrict__ cb2q,
    float4*       __restrict__ blockmin)  // [NTILES][MM]
{
    __shared__ short8 smem[2][1024];   // 32 KB: per buf A [0..512), B [512..1024)

    const int id   = blockIdx.x;
    const int xcd  = id & 7;
    const int slot = id >> 3;            // 0..255
    const int nt   = slot & 15;
    const int mt   = xcd * 16 + (slot >> 4);

    const int t    = threadIdx.x;
    const int wid  = t >> 6;
    const int lane = t & 63;
    const int wr   = wid >> 1, wc = wid & 1;
    const int l15  = lane & 15, l4 = lane >> 4;

    // acc[n][m]: codebook-col frag n, point-row frag m (operand-swapped MFMA)
    f32x4 acc[4][4];
    #pragma unroll
    for (int n = 0; n < 4; n++)
        #pragma unroll
        for (int m = 0; m < 4; m++) acc[n][m] = (f32x4){0.f, 0.f, 0.f, 0.f};

    const char* aSrc = (const char*)ah + (size_t)mt * 131072;   // 8 KB per ks
    const char* bSrc = (const char*)bh + (size_t)nt * 131072;

    auto STAGE = [&](int ks, int buf) {
        char* dst = (char*)&smem[buf][0];
        const char* as = aSrc + (size_t)ks * 8192;
        const char* bs = bSrc + (size_t)ks * 8192;
        #pragma unroll
        for (int j = 0; j < 2; j++) {
            int c = wid * 2 + j;
            GLDS(as + c * 1024 + lane * 16, dst + c * 1024);
            GLDS(bs + c * 1024 + lane * 16, dst + 8192 + c * 1024);
        }
    };

    int buf = 0;
    STAGE(0, 0);

    for (int ks = 0; ks < NSTEPS; ks++) {
        __syncthreads();
        if (ks < NSTEPS - 1) STAGE(ks + 1, buf ^ 1);

        short8 af[4], bf[4];
        #pragma unroll
        for (int m = 0; m < 4; m++) af[m] = smem[buf][wr * 256 + m * 64 + lane];
        #pragma unroll
        for (int n = 0; n < 4; n++) bf[n] = smem[buf][512 + wc * 256 + n * 64 + lane];

        #pragma unroll
        for (int n = 0; n < 4; n++)
            #pragma unroll
            for (int m = 0; m < 4; m++)
                acc[n][m] = __builtin_amdgcn_mfma_f32_16x16x32_bf16(bf[n], af[m], acc[n][m], 0, 0, 0);

        buf ^= 1;
    }

    // ---- epilogue: in-register per-row top-2 scan ----
    // acc[n][m][r]: point row = wr*64 + m*16 + l15 ; col = wc*64 + n*16 + l4*4 + r
    // No barrier needed before pairs writes: last K-step only read smem[1],
    // pairs live in smem[0] (last read of smem[0] drained at the ks=15 barrier).
    float4* pairs = (float4*)&smem[0][0];   // [128 rows][2 wc]

    f32x4 c2v[4];
    #pragma unroll
    for (int n = 0; n < 4; n++)
        c2v[n] = *(const f32x4*)&cb2q[nt * 128 + wc * 64 + n * 16 + (l4 << 2)];

    const int kbase = nt * 128 + wc * 64 + (l4 << 2);

    #pragma unroll
    for (int m = 0; m < 4; m++) {
        float v1 = 3.4e38f, v2 = 3.4e38f;
        int jm = 0;
        #pragma unroll
        for (int n = 0; n < 4; n++) {
            #pragma unroll
            for (int r = 0; r < 4; r++) {
                float d = fmaf(-2.f, acc[n][m][r], c2v[n][r]);
                bool b = d < v1;                       // ties arbitrary: exact
                v2 = fminf(fmaxf(d, v1), v2);          // refine pass (crru) owns
                jm = b ? (n * 4 + r) : jm;             // index tie-breaking
                v1 = fminf(d, v1);
            }
        }
        int i1 = kbase + ((jm >> 2) << 4) + (jm & 3);
        #pragma unroll
        for (int off = 16; off <= 32; off <<= 1) {     // merge 4 l4-lanes of this row
            float w1 = __shfl_xor(v1, off);
            float w2 = __shfl_xor(v2, off);
            int   j1 = __shfl_xor(i1, off);
            bool b = w1 < v1;
            v2 = fminf(fminf(fmaxf(w1, v1), v2), w2);  // 2nd-min of union
            i1 = b ? j1 : i1;
            v1 = fminf(w1, v1);
        }
        if (l4 == 0)
            pairs[((wr << 6) + (m << 4) + l15) * 2 + wc] =
                make_float4(v1, __int_as_float(i1), v2, 0.f);
    }
    __syncthreads();

    if (t < BMt) {
        float4 p0 = pairs[t * 2], p1 = pairs[t * 2 + 1];
        bool b = p1.x < p0.x;
        float v2 = fminf(fminf(fmaxf(p1.x, p0.x), p0.z), p1.z);
        int   i1 = b ? __float_as_int(p1.y) : __float_as_int(p0.y);
        float v1 = fminf(p1.x, p0.x);
        blockmin[(size_t)nt * MM + mt * BMt + t] =
            make_float4(v1, __int_as_float(i1), v2, 0.f);
    }
}

// ---------------- combine + windowed exact refine (4-wide group-parallel) + update ----------------
// one wave per row; 4 groups of 16 lanes evaluate 4 candidate columns concurrently.
__global__ __launch_bounds__(256) void crru_kernel(
    const float4* __restrict__ blockmin,
    const float*  __restrict__ cbq,
    const float*  __restrict__ cb2q,
    float*        __restrict__ resid,
    float*        __restrict__ idx_out,
    short8*       __restrict__ ah,
    int q)
{
    __shared__ float rs[4][DD];          // 8 KB: per-wave resid row
    const int wid  = threadIdx.x >> 6;
    const int lane = threadIdx.x & 63;
    const int row  = blockIdx.x * 4 + wid;
    const int grp  = lane >> 4, gl = lane & 15;
    const float W  = 2.0f + 0.3f * q;    // proven coverage window (R7-R9)

    float4 p = blockmin[(size_t)(lane & 15) * MM + row];
    const float tv1 = p.x, tv2 = p.z;
    const int   ti1 = __float_as_int(p.y);

    float g1 = tv1;
    #pragma unroll
    for (int off = 8; off >= 1; off >>= 1) g1 = fminf(g1, __shfl_xor(g1, off));
    const float thr = g1 + W;

    float* rrow = resid + (size_t)row * DD + lane * 8;
    float4 r0 = *(const float4*)rrow;
    float4 r1 = *(const float4*)(rrow + 4);
    *(float4*)&rs[wid][lane * 8]     = r0;
    *(float4*)&rs[wid][lane * 8 + 4] = r1;   // same-wave RAW: compiler inserts lgkmcnt

    const bool isT = lane < 16;
    unsigned long long hot  = __ballot(isT && (tv2 < thr));
    unsigned long long cand = __ballot(isT && (tv1 < thr)) & ~hot;

    float be = 3.4e38f; int bk = 0x7FFFFFFF;

    // evaluate up to 4 columns (k<0 = inactive) with 16-lane-group exact fp32 dots
    auto eval4 = [&](int k0, int k1, int k2, int k3) {
        int kg = (grp == 0) ? k0 : (grp == 1) ? k1 : (grp == 2) ? k2 : k3;
        float d = 0.f;
        if (kg >= 0) {
            const float* cp = cbq + (size_t)kg * DD + gl * 32;
            const float* rp = &rs[wid][gl * 32];
            #pragma unroll
            for (int j = 0; j < 8; j++) {
                float4 c = *(const float4*)(cp + j * 4);
                float4 r = *(const float4*)(rp + j * 4);
                d = fmaf(r.x, c.x, d); d = fmaf(r.y, c.y, d);
                d = fmaf(r.z, c.z, d); d = fmaf(r.w, c.w, d);
            }
        }
        #pragma unroll
        for (int off = 8; off >= 1; off >>= 1) d += __shfl_xor(d, off);
        #pragma unroll
        for (int g = 0; g < 4; g++) {
            float dg = __shfl(d, g * 16);
            int kg2 = (g == 0) ? k0 : (g == 1) ? k1 : (g == 2) ? k2 : k3;
            if (kg2 >= 0) {
                float e = fmaf(-2.f, dg, cb2q[kg2]);
                if (e < be || (e == be && kg2 < bk)) { be = e; bk = kg2; }
            }
        }
    };

    // candidate tiles' approx-best columns, 4 at a time
    while (cand) {
        int k[4] = {-1, -1, -1, -1};
        #pragma unroll
        for (int j = 0; j < 4; j++) {
            if (cand) {
                int L = __ffsll((unsigned long long)cand) - 1;
                cand &= cand - 1;
                k[j] = __shfl(ti1, L);
            }
        }
        eval4(k[0], k[1], k[2], k[3]);
    }
    // hot tiles: all 128 columns, 4 at a time (iterations independent -> pipelined)
    while (hot) {
        int L = __ffsll((unsigned long long)hot) - 1;
        hot &= hot - 1;
        int base = L * 128;
        for (int c = 0; c < 128; c += 4)
            eval4(base + c, base + c + 1, base + c + 2, base + c + 3);
    }
    const int winner = bk;

    if (lane == 0) {
        int b = row >> 11, l = row & (LL - 1);
        idx_out[((size_t)b * QQ + q) * LL + l] = (float)winner;
    }

    const float* cw = cbq + (size_t)winner * DD + lane * 8;
    float4 c0 = *(const float4*)cw;
    float4 c1 = *(const float4*)(cw + 4);
    float4 n0 = make_float4(r0.x - c0.x, r0.y - c0.y, r0.z - c0.z, r0.w - c0.w);
    float4 n1 = make_float4(r1.x - c1.x, r1.y - c1.y, r1.z - c1.z, r1.w - c1.w);
    *(float4*)rrow       = n0;
    *(float4*)(rrow + 4) = n1;

    if (q < QQ - 1) {
        short8 h;
        h[0] = (short)f2bf(n0.x); h[1] = (short)f2bf(n0.y);
        h[2] = (short)f2bf(n0.z); h[3] = (short)f2bf(n0.w);
        h[4] = (short)f2bf(n1.x); h[5] = (short)f2bf(n1.y);
        h[6] = (short)f2bf(n1.z); h[7] = (short)f2bf(n1.w);
        ah[a_frag_idx(row, lane)] = h;
    }
}

// ---------------- quantized = x - r_final ----------------
__global__ __launch_bounds__(256) void final_kernel(const float* __restrict__ x,
                                                    float* __restrict__ qout) {
    size_t i = (size_t)blockIdx.x * 256 + threadIdx.x;
    float4 xv = ((const float4*)x)[i];
    float4 rv = ((float4*)qout)[i];
    ((float4*)qout)[i] = make_float4(xv.x - rv.x, xv.y - rv.y, xv.z - rv.z, xv.w - rv.w);
}

extern "C" void kernel_launch(void* const* d_in, const int* in_sizes, int n_in,
                              void* d_out, int out_size, void* d_ws, size_t ws_size,
                              hipStream_t stream) {
    (void)in_sizes; (void)n_in; (void)out_size; (void)ws_size;
    const float* x  = (const float*)d_in[0];
    const float* cb = (const float*)d_in[1];
    float* out = (float*)d_out;

    float* idx_out = out;                           // BB*QQ*LL floats
    float* resid   = out + (size_t)BB * QQ * LL;    // doubles as quantized output

    char* w = (char*)d_ws;
    float*  cb2      = (float*)(w);                 // 64 KB
    float4* blockmin = (float4*)(w + 0x10000);      // 4 MB  -> ends 0x410000
    short8* ah       = (short8*)(w + 0x410000);     // 16 MB -> ends 0x1410000
    short8* bh       = (short8*)(w + 0x1410000);    // 2 MB  -> ends 0x1610000 (~23 MB)

    cb2_kernel<<<QQ * KK / 4, 256, 0, stream>>>(cb, cb2);
    aprep0_kernel<<<MM / 4, 256, 0, stream>>>(x, resid, ah);

    for (int q = 0; q < QQ; q++) {
        const float* cbq = cb + (size_t)q * KK * DD;
        const float* c2q = cb2 + (size_t)q * KK;

        bprep_kernel<<<KK * DD / 8 / 256, 256, 0, stream>>>(cbq, bh);

        gemm_argmin_kernel<<<NTILES * MTILES, 256, 0, stream>>>(ah, bh, c2q, blockmin);

        crru_kernel<<<MM / 4, 256, 0, stream>>>(blockmin, cbq, c2q, resid,
                                                idx_out, ah, q);
    }

    final_kernel<<<MM * DD / 4 / 256, 256, 0, stream>>>(x, resid);
}

// Round 2
// 782.880 us; speedup vs baseline: 1.5025x; 1.2152x over previous
//
#include <hip/hip_runtime.h>

#define BB 8
#define LL 2048
#define DD 512
#define QQ 8
#define KK 2048
#define MM (BB*LL)      // 16384 points

#define BMt 128         // block tile M (2 wr-waves x 64)
#define BNt 128         // block tile N (2 wc-waves x 64)
#define NSTEPS 16       // DD/32
#define NTILES (KK/BNt) // 16
#define MTILES (MM/BMt) // 128

typedef __attribute__((ext_vector_type(8))) short short8;
typedef __attribute__((ext_vector_type(4))) float f32x4;

#define GLDS(src, dst) __builtin_amdgcn_global_load_lds( \
    (const __attribute__((address_space(1))) void*)(src), \
    (__attribute__((address_space(3))) void*)(dst), 16, 0, 0)

__device__ __forceinline__ ushort f2bf(float f) {
    uint u = __float_as_uint(f);
    u += 0x7FFFu + ((u >> 16) & 1u);
    return (ushort)(u >> 16);
}

// ---------------- cb2: fp32 squared norms ----------------
__global__ __launch_bounds__(256) void cb2_kernel(const float* __restrict__ cb,
                                                  float* __restrict__ cb2) {
    int row  = blockIdx.x * 4 + (threadIdx.x >> 6);
    int lane = threadIdx.x & 63;
    const float* r = cb + (size_t)row * DD + lane * 8;
    float4 a = *(const float4*)r;
    float4 b = *(const float4*)(r + 4);
    float s = a.x*a.x + a.y*a.y + a.z*a.z + a.w*a.w
            + b.x*b.x + b.y*b.y + b.z*b.z + b.w*b.w;
    #pragma unroll
    for (int off = 32; off >= 1; off >>= 1) s += __shfl_xor(s, off);
    if (lane == 0) cb2[row] = s;
}

// ---------------- codebook hi-part, wave-contiguous frag order ----------------
// frag idx = (nt*16+ks)*512 + colblk*64 + kk*16 + colr   (nt: 16 tiles of 128 cols)
__global__ __launch_bounds__(256) void bprep_kernel(const float* __restrict__ cbq,
                                                    short8* __restrict__ bh) {
    int r = blockIdx.x * 256 + threadIdx.x;   // 0..131071, write-coalesced
    int colr   = r & 15;
    int kk     = (r >> 4) & 3;
    int colblk = (r >> 6) & 7;
    int ks     = (r >> 9) & 15;
    int nt     = r >> 13;
    const float* src = cbq + (size_t)(nt * 128 + colblk * 16 + colr) * DD + ks * 32 + kk * 8;
    float f[8];
    *(float4*)&f[0] = *(const float4*)src;
    *(float4*)&f[4] = *(const float4*)(src + 4);
    short8 h8;
    #pragma unroll
    for (int j = 0; j < 8; j++) h8[j] = (short)f2bf(f[j]);
    bh[r] = h8;
}

// A frag index for point row, lane (lane covers d = lane*8): 128-row tiles
__device__ __forceinline__ size_t a_frag_idx(int row, int lane) {
    int mt = row >> 7, rowblk = (row >> 4) & 7, rowr = row & 15;
    int ks = lane >> 2, kk = lane & 3;
    return ((size_t)(mt * 16 + ks)) * 512 + rowblk * 64 + kk * 16 + rowr;
}

// ---------------- level-0 A prep: resid <- x, ah <- bf16(x) frags ----------------
__global__ __launch_bounds__(256) void aprep0_kernel(const float* __restrict__ x,
                                                     float* __restrict__ resid,
                                                     short8* __restrict__ ah) {
    const int wid  = threadIdx.x >> 6;
    const int lane = threadIdx.x & 63;
    const int row  = blockIdx.x * 4 + wid;
    const float* src = x + (size_t)row * DD + lane * 8;
    float4 v0 = *(const float4*)src;
    float4 v1 = *(const float4*)(src + 4);
    float* dst = resid + (size_t)row * DD + lane * 8;
    *(float4*)dst       = v0;
    *(float4*)(dst + 4) = v1;
    short8 h;
    h[0] = (short)f2bf(v0.x); h[1] = (short)f2bf(v0.y);
    h[2] = (short)f2bf(v0.z); h[3] = (short)f2bf(v0.w);
    h[4] = (short)f2bf(v1.x); h[5] = (short)f2bf(v1.y);
    h[6] = (short)f2bf(v1.z); h[7] = (short)f2bf(v1.w);
    ah[a_frag_idx(row, lane)] = h;
}

// ---------------- 1-term bf16 GEMM + per-tile (v1,i1,v2) ----------------
// 2048 blocks x 256 thr; XCD-chunked remap; 4 waves (2x2), wave tile 64x64.
// MFMA operands SWAPPED (acc = mfma(bf, af)): C/D layout gives each lane
// 16 cols of ONE point row per m-frag -> in-register top-2 scan, 2 shfl stages.
__global__ __launch_bounds__(256, 4) void gemm_argmin_kernel(
    const short8* __restrict__ ah,
    const short8* __restrict__ bh,
    const float*  __restrict__ cb2q,
    float4*       __restrict__ blockmin)  // [NTILES][MM]
{
    __shared__ short8 smem[2][1024];   // 32 KB: per buf A [0..512), B [512..1024)

    const int id   = blockIdx.x;
    const int xcd  = id & 7;
    const int slot = id >> 3;            // 0..255
    const int nt   = slot & 15;
    const int mt   = xcd * 16 + (slot >> 4);

    const int t    = threadIdx.x;
    const int wid  = t >> 6;
    const int lane = t & 63;
    const int wr   = wid >> 1, wc = wid & 1;
    const int l15  = lane & 15, l4 = lane >> 4;

    // acc[n][m]: codebook-col frag n, point-row frag m (operand-swapped MFMA)
    f32x4 acc[4][4];
    #pragma unroll
    for (int n = 0; n < 4; n++)
        #pragma unroll
        for (int m = 0; m < 4; m++) acc[n][m] = (f32x4){0.f, 0.f, 0.f, 0.f};

    const char* aSrc = (const char*)ah + (size_t)mt * 131072;   // 8 KB per ks
    const char* bSrc = (const char*)bh + (size_t)nt * 131072;

    auto STAGE = [&](int ks, int buf) {
        char* dst = (char*)&smem[buf][0];
        const char* as = aSrc + (size_t)ks * 8192;
        const char* bs = bSrc + (size_t)ks * 8192;
        #pragma unroll
        for (int j = 0; j < 2; j++) {
            int c = wid * 2 + j;
            GLDS(as + c * 1024 + lane * 16, dst + c * 1024);
            GLDS(bs + c * 1024 + lane * 16, dst + 8192 + c * 1024);
        }
    };

    int buf = 0;
    STAGE(0, 0);

    for (int ks = 0; ks < NSTEPS; ks++) {
        __syncthreads();
        if (ks < NSTEPS - 1) STAGE(ks + 1, buf ^ 1);

        short8 af[4], bf[4];
        #pragma unroll
        for (int m = 0; m < 4; m++) af[m] = smem[buf][wr * 256 + m * 64 + lane];
        #pragma unroll
        for (int n = 0; n < 4; n++) bf[n] = smem[buf][512 + wc * 256 + n * 64 + lane];

        #pragma unroll
        for (int n = 0; n < 4; n++)
            #pragma unroll
            for (int m = 0; m < 4; m++)
                acc[n][m] = __builtin_amdgcn_mfma_f32_16x16x32_bf16(bf[n], af[m], acc[n][m], 0, 0, 0);

        buf ^= 1;
    }

    // ---- epilogue: in-register per-row top-2 scan ----
    // acc[n][m][r]: point row = wr*64 + m*16 + l15 ; col = wc*64 + n*16 + l4*4 + r
    float4* pairs = (float4*)&smem[0][0];   // [128 rows][2 wc]

    f32x4 c2v[4];
    #pragma unroll
    for (int n = 0; n < 4; n++)
        c2v[n] = *(const f32x4*)&cb2q[nt * 128 + wc * 64 + n * 16 + (l4 << 2)];

    const int kbase = nt * 128 + wc * 64 + (l4 << 2);

    #pragma unroll
    for (int m = 0; m < 4; m++) {
        float v1 = 3.4e38f, v2 = 3.4e38f;
        int jm = 0;
        #pragma unroll
        for (int n = 0; n < 4; n++) {
            #pragma unroll
            for (int r = 0; r < 4; r++) {
                float d = fmaf(-2.f, acc[n][m][r], c2v[n][r]);
                bool b = d < v1;                       // ties arbitrary: exact
                v2 = fminf(fmaxf(d, v1), v2);          // refine pass (crru) owns
                jm = b ? (n * 4 + r) : jm;             // index tie-breaking
                v1 = fminf(d, v1);
            }
        }
        int i1 = kbase + ((jm >> 2) << 4) + (jm & 3);
        #pragma unroll
        for (int off = 16; off <= 32; off <<= 1) {     // merge 4 l4-lanes of this row
            float w1 = __shfl_xor(v1, off);
            float w2 = __shfl_xor(v2, off);
            int   j1 = __shfl_xor(i1, off);
            bool b = w1 < v1;
            v2 = fminf(fminf(fmaxf(w1, v1), v2), w2);  // 2nd-min of union
            i1 = b ? j1 : i1;
            v1 = fminf(w1, v1);
        }
        if (l4 == 0)
            pairs[((wr << 6) + (m << 4) + l15) * 2 + wc] =
                make_float4(v1, __int_as_float(i1), v2, 0.f);
    }
    __syncthreads();

    if (t < BMt) {
        float4 p0 = pairs[t * 2], p1 = pairs[t * 2 + 1];
        bool b = p1.x < p0.x;
        float v2 = fminf(fminf(fmaxf(p1.x, p0.x), p0.z), p1.z);
        int   i1 = b ? __float_as_int(p1.y) : __float_as_int(p0.y);
        float v1 = fminf(p1.x, p0.x);
        blockmin[(size_t)nt * MM + mt * BMt + t] =
            make_float4(v1, __int_as_float(i1), v2, 0.f);
    }
}

// ---------------- combine + windowed exact refine + update ----------------
// ONE BLOCK PER ROW: 16 groups of 16 lanes evaluate 16 candidate columns
// concurrently (was 4) -> worst-case (hot-tile-heavy) rows run 4x faster.
__global__ __launch_bounds__(256) void crru_kernel(
    const float4* __restrict__ blockmin,
    const float*  __restrict__ cbq,
    const float*  __restrict__ cb2q,
    float*        __restrict__ resid,
    float*        __restrict__ idx_out,
    short8*       __restrict__ ah,
    int q)
{
    __shared__ float rs[DD];             // 2 KB: this row's residual
    __shared__ int   hotlist[16];
    __shared__ int   candcol[16];
    __shared__ int   countS[2];          // nc, nh
    __shared__ float2 gbest[16];         // per-group (best, idx)
    __shared__ int   winnerS;

    const int row  = blockIdx.x;
    const int t    = threadIdx.x;
    const int wid  = t >> 6;
    const int lane = t & 63;
    const int grp  = t >> 4, gl = t & 15;
    const float W  = 2.0f + 0.3f * q;    // proven coverage window (R7-R9)

    // all threads: stage residual row into LDS (coalesced float2 each)
    {
        const float* rp = resid + (size_t)row * DD + t * 2;
        *(float2*)&rs[t * 2] = *(const float2*)rp;
    }

    // wave 0: tile classification -> compact work lists
    if (wid == 0) {
        float4 p = blockmin[(size_t)(lane & 15) * MM + row];
        const float tv1 = p.x, tv2 = p.z;
        const int   ti1 = __float_as_int(p.y);
        float g1 = tv1;
        #pragma unroll
        for (int off = 8; off >= 1; off >>= 1) g1 = fminf(g1, __shfl_xor(g1, off));
        const float thr = g1 + W;
        const bool isT = lane < 16;
        unsigned long long hot  = __ballot(isT && (tv2 < thr));
        unsigned long long cand = __ballot(isT && (tv1 < thr)) & ~hot;
        if (isT) {
            unsigned long long me = 1ull << lane;
            if (cand & me) candcol[__popcll(cand & (me - 1))] = ti1;
            if (hot & me)  hotlist[__popcll(hot & (me - 1))]  = lane;
            if (lane == 0) { countS[0] = (int)__popcll(cand);
                             countS[1] = (int)__popcll(hot); }
        }
    }
    __syncthreads();

    const int nc = countS[0], nh = countS[1];
    const int total = nc + nh * 128;

    float be = 3.4e38f; int bk = 0x7FFFFFFF;

    for (int i = grp; i < total; i += 16) {
        int col;
        if (i < nc) col = candcol[i];
        else { int j = i - nc; col = hotlist[j >> 7] * 128 + (j & 127); }
        const float* cp = cbq + (size_t)col * DD + gl * 32;
        const float* rp = &rs[gl * 32];
        float d = 0.f;
        #pragma unroll
        for (int j = 0; j < 8; j++) {
            float4 c = *(const float4*)(cp + j * 4);
            float4 r = *(const float4*)(rp + j * 4);
            d = fmaf(r.x, c.x, d); d = fmaf(r.y, c.y, d);
            d = fmaf(r.z, c.z, d); d = fmaf(r.w, c.w, d);
        }
        #pragma unroll
        for (int off = 8; off >= 1; off >>= 1) d += __shfl_xor(d, off);
        float e = fmaf(-2.f, d, cb2q[col]);
        if (e < be || (e == be && col < bk)) { be = e; bk = col; }
    }
    if (gl == 0) gbest[grp] = make_float2(be, __int_as_float(bk));
    __syncthreads();

    if (t < 16) {
        float2 g = gbest[t];
        float v = g.x; int k = __float_as_int(g.y);
        #pragma unroll
        for (int off = 8; off >= 1; off >>= 1) {
            float ov = __shfl_xor(v, off);
            int   ok = __shfl_xor(k, off);
            if (ov < v || (ov == v && ok < k)) { v = ov; k = ok; }
        }
        if (t == 0) winnerS = k;
    }
    __syncthreads();
    const int winner = winnerS;

    // wave 0: residual update + bf16 frag rewrite (8 floats/lane)
    if (wid == 0) {
        if (lane == 0) {
            int b = row >> 11, l = row & (LL - 1);
            idx_out[((size_t)b * QQ + q) * LL + l] = (float)winner;
        }
        const float* cw = cbq + (size_t)winner * DD + lane * 8;
        float4 c0 = *(const float4*)cw;
        float4 c1 = *(const float4*)(cw + 4);
        float4 r0 = *(const float4*)&rs[lane * 8];
        float4 r1 = *(const float4*)&rs[lane * 8 + 4];
        float4 n0 = make_float4(r0.x - c0.x, r0.y - c0.y, r0.z - c0.z, r0.w - c0.w);
        float4 n1 = make_float4(r1.x - c1.x, r1.y - c1.y, r1.z - c1.z, r1.w - c1.w);
        float* rrow = resid + (size_t)row * DD + lane * 8;
        *(float4*)rrow       = n0;
        *(float4*)(rrow + 4) = n1;
        if (q < QQ - 1) {
            short8 h;
            h[0] = (short)f2bf(n0.x); h[1] = (short)f2bf(n0.y);
            h[2] = (short)f2bf(n0.z); h[3] = (short)f2bf(n0.w);
            h[4] = (short)f2bf(n1.x); h[5] = (short)f2bf(n1.y);
            h[6] = (short)f2bf(n1.z); h[7] = (short)f2bf(n1.w);
            ah[a_frag_idx(row, lane)] = h;
        }
    }
}

// ---------------- quantized = x - r_final ----------------
__global__ __launch_bounds__(256) void final_kernel(const float* __restrict__ x,
                                                    float* __restrict__ qout) {
    size_t i = (size_t)blockIdx.x * 256 + threadIdx.x;
    float4 xv = ((const float4*)x)[i];
    float4 rv = ((float4*)qout)[i];
    ((float4*)qout)[i] = make_float4(xv.x - rv.x, xv.y - rv.y, xv.z - rv.z, xv.w - rv.w);
}

extern "C" void kernel_launch(void* const* d_in, const int* in_sizes, int n_in,
                              void* d_out, int out_size, void* d_ws, size_t ws_size,
                              hipStream_t stream) {
    (void)in_sizes; (void)n_in; (void)out_size; (void)ws_size;
    const float* x  = (const float*)d_in[0];
    const float* cb = (const float*)d_in[1];
    float* out = (float*)d_out;

    float* idx_out = out;                           // BB*QQ*LL floats
    float* resid   = out + (size_t)BB * QQ * LL;    // doubles as quantized output

    char* w = (char*)d_ws;
    float*  cb2      = (float*)(w);                 // 64 KB
    float4* blockmin = (float4*)(w + 0x10000);      // 4 MB  -> ends 0x410000
    short8* ah       = (short8*)(w + 0x410000);     // 16 MB -> ends 0x1410000
    short8* bh       = (short8*)(w + 0x1410000);    // 2 MB  -> ends 0x1610000 (~23 MB)

    cb2_kernel<<<QQ * KK / 4, 256, 0, stream>>>(cb, cb2);
    aprep0_kernel<<<MM / 4, 256, 0, stream>>>(x, resid, ah);

    for (int q = 0; q < QQ; q++) {
        const float* cbq = cb + (size_t)q * KK * DD;
        const float* c2q = cb2 + (size_t)q * KK;

        bprep_kernel<<<KK * DD / 8 / 256, 256, 0, stream>>>(cbq, bh);

        gemm_argmin_kernel<<<NTILES * MTILES, 256, 0, stream>>>(ah, bh, c2q, blockmin);

        crru_kernel<<<MM, 256, 0, stream>>>(blockmin, cbq, c2q, resid,
                                            idx_out, ah, q);
    }

    final_kernel<<<MM * DD / 4 / 256, 256, 0, stream>>>(x, resid);
}

// Round 3
// 668.736 us; speedup vs baseline: 1.7590x; 1.1707x over previous
//
#include <hip/hip_runtime.h>

#define BB 8
#define LL 2048
#define DD 512
#define QQ 8
#define KK 2048
#define MM (BB*LL)      // 16384 points

#define BMt 128         // block tile M (2 wr-waves x 64)
#define BNt 128         // block tile N (2 wc-waves x 64)
#define NSTEPS 16       // DD/32
#define NTILES (KK/BNt) // 16
#define MTILES (MM/BMt) // 128

typedef __attribute__((ext_vector_type(8))) short short8;
typedef __attribute__((ext_vector_type(4))) float f32x4;

#define GLDS(src, dst) __builtin_amdgcn_global_load_lds( \
    (const __attribute__((address_space(1))) void*)(src), \
    (__attribute__((address_space(3))) void*)(dst), 16, 0, 0)

__device__ __forceinline__ ushort f2bf(float f) {
    uint u = __float_as_uint(f);
    u += 0x7FFFu + ((u >> 16) & 1u);
    return (ushort)(u >> 16);
}

// ---------------- cb2: fp32 squared norms ----------------
__global__ __launch_bounds__(256) void cb2_kernel(const float* __restrict__ cb,
                                                  float* __restrict__ cb2) {
    int row  = blockIdx.x * 4 + (threadIdx.x >> 6);
    int lane = threadIdx.x & 63;
    const float* r = cb + (size_t)row * DD + lane * 8;
    float4 a = *(const float4*)r;
    float4 b = *(const float4*)(r + 4);
    float s = a.x*a.x + a.y*a.y + a.z*a.z + a.w*a.w
            + b.x*b.x + b.y*b.y + b.z*b.z + b.w*b.w;
    #pragma unroll
    for (int off = 32; off >= 1; off >>= 1) s += __shfl_xor(s, off);
    if (lane == 0) cb2[row] = s;
}

// ---------------- codebook hi-part, wave-contiguous frag order ----------------
// frag idx = (nt*16+ks)*512 + colblk*64 + kk*16 + colr   (nt: 16 tiles of 128 cols)
__global__ __launch_bounds__(256) void bprep_kernel(const float* __restrict__ cbq,
                                                    short8* __restrict__ bh) {
    int r = blockIdx.x * 256 + threadIdx.x;   // 0..131071, write-coalesced
    int colr   = r & 15;
    int kk     = (r >> 4) & 3;
    int colblk = (r >> 6) & 7;
    int ks     = (r >> 9) & 15;
    int nt     = r >> 13;
    const float* src = cbq + (size_t)(nt * 128 + colblk * 16 + colr) * DD + ks * 32 + kk * 8;
    float f[8];
    *(float4*)&f[0] = *(const float4*)src;
    *(float4*)&f[4] = *(const float4*)(src + 4);
    short8 h8;
    #pragma unroll
    for (int j = 0; j < 8; j++) h8[j] = (short)f2bf(f[j]);
    bh[r] = h8;
}

// A frag index for point row, lane (lane covers d = lane*8): 128-row tiles
__device__ __forceinline__ size_t a_frag_idx(int row, int lane) {
    int mt = row >> 7, rowblk = (row >> 4) & 7, rowr = row & 15;
    int ks = lane >> 2, kk = lane & 3;
    return ((size_t)(mt * 16 + ks)) * 512 + rowblk * 64 + kk * 16 + rowr;
}

// ---------------- level-0 A prep: resid <- x, ah <- bf16(x) frags ----------------
__global__ __launch_bounds__(256) void aprep0_kernel(const float* __restrict__ x,
                                                     float* __restrict__ resid,
                                                     short8* __restrict__ ah) {
    const int wid  = threadIdx.x >> 6;
    const int lane = threadIdx.x & 63;
    const int row  = blockIdx.x * 4 + wid;
    const float* src = x + (size_t)row * DD + lane * 8;
    float4 v0 = *(const float4*)src;
    float4 v1 = *(const float4*)(src + 4);
    float* dst = resid + (size_t)row * DD + lane * 8;
    *(float4*)dst       = v0;
    *(float4*)(dst + 4) = v1;
    short8 h;
    h[0] = (short)f2bf(v0.x); h[1] = (short)f2bf(v0.y);
    h[2] = (short)f2bf(v0.z); h[3] = (short)f2bf(v0.w);
    h[4] = (short)f2bf(v1.x); h[5] = (short)f2bf(v1.y);
    h[6] = (short)f2bf(v1.z); h[7] = (short)f2bf(v1.w);
    ah[a_frag_idx(row, lane)] = h;
}

// ---------------- 1-term bf16 GEMM + per-tile (v1, candidate bitmask) ----------------
// 2048 blocks x 256 thr; XCD-chunked remap; 4 waves (2x2), wave tile 64x64.
// Operand-swapped MFMA: lane holds 16 cols of ONE row per m-frag.
// Epilogue: phase A tile-min (cross-l4 shfl + cross-wc LDS), phase B 128-bit
// mask of cols with d < v1_tile + W (exact superset of downstream needs).
__global__ __launch_bounds__(256, 4) void gemm_argmin_kernel(
    const short8* __restrict__ ah,
    const short8* __restrict__ bh,
    const float*  __restrict__ cb2q,
    float*        __restrict__ blockv1,    // [NTILES][MM]
    uint4*        __restrict__ blockmask,  // [NTILES][MM]
    float W)
{
    __shared__ short8 smem[2][1024];   // 32 KB: per buf A [0..512), B [512..1024)

    const int id   = blockIdx.x;
    const int xcd  = id & 7;
    const int slot = id >> 3;            // 0..255
    const int nt   = slot & 15;
    const int mt   = xcd * 16 + (slot >> 4);

    const int t    = threadIdx.x;
    const int wid  = t >> 6;
    const int lane = t & 63;
    const int wr   = wid >> 1, wc = wid & 1;
    const int l15  = lane & 15, l4 = lane >> 4;

    // acc[n][m]: codebook-col frag n, point-row frag m (operand-swapped MFMA)
    f32x4 acc[4][4];
    #pragma unroll
    for (int n = 0; n < 4; n++)
        #pragma unroll
        for (int m = 0; m < 4; m++) acc[n][m] = (f32x4){0.f, 0.f, 0.f, 0.f};

    const char* aSrc = (const char*)ah + (size_t)mt * 131072;   // 8 KB per ks
    const char* bSrc = (const char*)bh + (size_t)nt * 131072;

    auto STAGE = [&](int ks, int buf) {
        char* dst = (char*)&smem[buf][0];
        const char* as = aSrc + (size_t)ks * 8192;
        const char* bs = bSrc + (size_t)ks * 8192;
        #pragma unroll
        for (int j = 0; j < 2; j++) {
            int c = wid * 2 + j;
            GLDS(as + c * 1024 + lane * 16, dst + c * 1024);
            GLDS(bs + c * 1024 + lane * 16, dst + 8192 + c * 1024);
        }
    };

    int buf = 0;
    STAGE(0, 0);

    for (int ks = 0; ks < NSTEPS; ks++) {
        __syncthreads();
        if (ks < NSTEPS - 1) STAGE(ks + 1, buf ^ 1);

        short8 af[4], bf[4];
        #pragma unroll
        for (int m = 0; m < 4; m++) af[m] = smem[buf][wr * 256 + m * 64 + lane];
        #pragma unroll
        for (int n = 0; n < 4; n++) bf[n] = smem[buf][512 + wc * 256 + n * 64 + lane];

        #pragma unroll
        for (int n = 0; n < 4; n++)
            #pragma unroll
            for (int m = 0; m < 4; m++)
                acc[n][m] = __builtin_amdgcn_mfma_f32_16x16x32_bf16(bf[n], af[m], acc[n][m], 0, 0, 0);

        buf ^= 1;
    }

    // ---- epilogue ----
    // acc[n][m][r]: row = wr*64 + m*16 + l15 ; col = wc*64 + n*16 + l4*4 + r
    // Last K-step read smem[1]; epilogue scratch lives in smem[0] (first 3 KB),
    // so no barrier needed before phase-A writes.
    float* halfmin = (float*)&smem[0][0];                                   // [128][2]
    unsigned long long* maskS = (unsigned long long*)((char*)&smem[0][0] + 1024); // [128][2]

    f32x4 c2v[4];
    #pragma unroll
    for (int n = 0; n < 4; n++)
        c2v[n] = *(const f32x4*)&cb2q[nt * 128 + wc * 64 + n * 16 + (l4 << 2)];

    // phase A: per-row per-wc-half min
    #pragma unroll
    for (int m = 0; m < 4; m++) {
        float v1 = 3.4e38f;
        #pragma unroll
        for (int n = 0; n < 4; n++)
            #pragma unroll
            for (int r = 0; r < 4; r++)
                v1 = fminf(v1, fmaf(-2.f, acc[n][m][r], c2v[n][r]));
        v1 = fminf(v1, __shfl_xor(v1, 16));
        v1 = fminf(v1, __shfl_xor(v1, 32));
        if (l4 == 0) halfmin[((wr << 6) + (m << 4) + l15) * 2 + wc] = v1;
    }
    __syncthreads();

    // phase B: candidate mask at v1_tile + W
    #pragma unroll
    for (int m = 0; m < 4; m++) {
        int rowl = (wr << 6) + (m << 4) + l15;
        float vt = fminf(halfmin[rowl * 2], halfmin[rowl * 2 + 1]);
        float thrm = vt + W;
        unsigned long long bits = 0;
        #pragma unroll
        for (int n = 0; n < 4; n++)
            #pragma unroll
            for (int r = 0; r < 4; r++) {
                float d = fmaf(-2.f, acc[n][m][r], c2v[n][r]);
                if (d < thrm) bits |= 1ull << (n * 16 + (l4 << 2) + r);
            }
        bits |= __shfl_xor(bits, 16);
        bits |= __shfl_xor(bits, 32);
        if (l4 == 0) maskS[rowl * 2 + wc] = bits;
    }
    __syncthreads();

    // phase C: write v1 + 128-bit mask per row
    if (t < BMt) {
        float vt = fminf(halfmin[t * 2], halfmin[t * 2 + 1]);
        unsigned long long m0 = maskS[t * 2], m1 = maskS[t * 2 + 1];
        size_t o = (size_t)nt * MM + mt * BMt + t;
        blockv1[o] = vt;
        blockmask[o] = make_uint4((uint)m0, (uint)(m0 >> 32),
                                  (uint)m1, (uint)(m1 >> 32));
    }
}

// ---------------- combine + exact refine of masked candidates + update ----------------
// one block per row; 16 groups of 16 lanes strip-mine the compact candidate list.
__global__ __launch_bounds__(256) void crru_kernel(
    const float*  __restrict__ blockv1,
    const uint4*  __restrict__ blockmask,
    const float*  __restrict__ cbq,
    const float*  __restrict__ cb2q,
    float*        __restrict__ resid,
    float*        __restrict__ idx_out,
    short8*       __restrict__ ah,
    int q, float W)
{
    __shared__ float rs[DD];             // 2 KB: this row's residual
    __shared__ int   candcol[NTILES * 128];  // 8 KB worst case (cannot overflow)
    __shared__ int   totalS;
    __shared__ float2 gbest[16];
    __shared__ int   winnerS;

    const int row  = blockIdx.x;
    const int t    = threadIdx.x;
    const int wid  = t >> 6;
    const int lane = t & 63;
    const int grp  = t >> 4, gl = t & 15;

    // all threads: stage residual row into LDS (coalesced float2 each)
    {
        const float* rp = resid + (size_t)row * DD + t * 2;
        *(float2*)&rs[t * 2] = *(const float2*)rp;
    }

    // wave 0: g1 reduce + compact candidate list from masks
    if (wid == 0) {
        const bool isT = lane < NTILES;
        float v1 = 3.4e38f;
        uint4 mk = make_uint4(0, 0, 0, 0);
        if (isT) {
            size_t o = (size_t)lane * MM + row;
            v1 = blockv1[o];
            mk = blockmask[o];
        }
        float g1 = v1;
        #pragma unroll
        for (int off = 8; off >= 1; off >>= 1) g1 = fminf(g1, __shfl_xor(g1, off));
        g1 = __shfl(g1, 0);
        const float thr = g1 + W;

        // tiles with v1 >= thr contribute nothing (all their d >= v1 >= thr)
        bool active = isT && (v1 < thr);
        unsigned long long lo = active ? (((unsigned long long)mk.y << 32) | mk.x) : 0ull;
        unsigned long long hi = active ? (((unsigned long long)mk.w << 32) | mk.z) : 0ull;
        int cnt = __popcll(lo) + __popcll(hi);

        // inclusive scan over lanes 0..15
        int inc = cnt;
        #pragma unroll
        for (int off = 1; off < 16; off <<= 1) {
            int y = __shfl_up(inc, off);
            if ((lane & 63) >= off) inc += y;
        }
        if (lane == 15) totalS = inc;
        int o = inc - cnt;
        int base = lane * 128;
        while (lo) { int b = __ffsll(lo) - 1; lo &= lo - 1; candcol[o++] = base + b; }
        while (hi) { int b = __ffsll(hi) - 1; hi &= hi - 1; candcol[o++] = base + 64 + b; }
    }
    __syncthreads();

    const int total = totalS;
    float be = 3.4e38f; int bk = 0x7FFFFFFF;

    for (int i = grp; i < total; i += 16) {
        int col = candcol[i];
        const float* cp = cbq + (size_t)col * DD + gl * 32;
        const float* rp = &rs[gl * 32];
        float d = 0.f;
        #pragma unroll
        for (int j = 0; j < 8; j++) {
            float4 c = *(const float4*)(cp + j * 4);
            float4 r = *(const float4*)(rp + j * 4);
            d = fmaf(r.x, c.x, d); d = fmaf(r.y, c.y, d);
            d = fmaf(r.z, c.z, d); d = fmaf(r.w, c.w, d);
        }
        #pragma unroll
        for (int off = 8; off >= 1; off >>= 1) d += __shfl_xor(d, off);
        float e = fmaf(-2.f, d, cb2q[col]);
        if (e < be || (e == be && col < bk)) { be = e; bk = col; }
    }
    if (gl == 0) gbest[grp] = make_float2(be, __int_as_float(bk));
    __syncthreads();

    if (t < 16) {
        float2 g = gbest[t];
        float v = g.x; int k = __float_as_int(g.y);
        #pragma unroll
        for (int off = 8; off >= 1; off >>= 1) {
            float ov = __shfl_xor(v, off);
            int   ok = __shfl_xor(k, off);
            if (ov < v || (ov == v && ok < k)) { v = ov; k = ok; }
        }
        if (t == 0) winnerS = k;
    }
    __syncthreads();
    const int winner = winnerS;

    // wave 0: residual update + bf16 frag rewrite (8 floats/lane)
    if (wid == 0) {
        if (lane == 0) {
            int b = row >> 11, l = row & (LL - 1);
            idx_out[((size_t)b * QQ + q) * LL + l] = (float)winner;
        }
        const float* cw = cbq + (size_t)winner * DD + lane * 8;
        float4 c0 = *(const float4*)cw;
        float4 c1 = *(const float4*)(cw + 4);
        float4 r0 = *(const float4*)&rs[lane * 8];
        float4 r1 = *(const float4*)&rs[lane * 8 + 4];
        float4 n0 = make_float4(r0.x - c0.x, r0.y - c0.y, r0.z - c0.z, r0.w - c0.w);
        float4 n1 = make_float4(r1.x - c1.x, r1.y - c1.y, r1.z - c1.z, r1.w - c1.w);
        float* rrow = resid + (size_t)row * DD + lane * 8;
        *(float4*)rrow       = n0;
        *(float4*)(rrow + 4) = n1;
        if (q < QQ - 1) {
            short8 h;
            h[0] = (short)f2bf(n0.x); h[1] = (short)f2bf(n0.y);
            h[2] = (short)f2bf(n0.z); h[3] = (short)f2bf(n0.w);
            h[4] = (short)f2bf(n1.x); h[5] = (short)f2bf(n1.y);
            h[6] = (short)f2bf(n1.z); h[7] = (short)f2bf(n1.w);
            ah[a_frag_idx(row, lane)] = h;
        }
    }
}

// ---------------- quantized = x - r_final ----------------
__global__ __launch_bounds__(256) void final_kernel(const float* __restrict__ x,
                                                    float* __restrict__ qout) {
    size_t i = (size_t)blockIdx.x * 256 + threadIdx.x;
    float4 xv = ((const float4*)x)[i];
    float4 rv = ((float4*)qout)[i];
    ((float4*)qout)[i] = make_float4(xv.x - rv.x, xv.y - rv.y, xv.z - rv.z, xv.w - rv.w);
}

extern "C" void kernel_launch(void* const* d_in, const int* in_sizes, int n_in,
                              void* d_out, int out_size, void* d_ws, size_t ws_size,
                              hipStream_t stream) {
    (void)in_sizes; (void)n_in; (void)out_size; (void)ws_size;
    const float* x  = (const float*)d_in[0];
    const float* cb = (const float*)d_in[1];
    float* out = (float*)d_out;

    float* idx_out = out;                           // BB*QQ*LL floats
    float* resid   = out + (size_t)BB * QQ * LL;    // doubles as quantized output

    char* w = (char*)d_ws;
    float*  cb2       = (float*)(w);                 // 64 KB
    float*  blockv1   = (float*)(w + 0x10000);       // 1 MB  -> ends 0x110000
    uint4*  blockmask = (uint4*)(w + 0x110000);      // 4 MB  -> ends 0x510000
    short8* ah        = (short8*)(w + 0x510000);     // 16 MB -> ends 0x1510000
    short8* bh        = (short8*)(w + 0x1510000);    // 2 MB  -> ends 0x1710000 (~24 MB)

    cb2_kernel<<<QQ * KK / 4, 256, 0, stream>>>(cb, cb2);
    aprep0_kernel<<<MM / 4, 256, 0, stream>>>(x, resid, ah);

    for (int q = 0; q < QQ; q++) {
        const float* cbq = cb + (size_t)q * KK * DD;
        const float* c2q = cb2 + (size_t)q * KK;
        const float W = 2.0f + 0.3f * q;   // proven coverage window (R7-R9)

        bprep_kernel<<<KK * DD / 8 / 256, 256, 0, stream>>>(cbq, bh);

        gemm_argmin_kernel<<<NTILES * MTILES, 256, 0, stream>>>(ah, bh, c2q,
                                                                blockv1, blockmask, W);

        crru_kernel<<<MM, 256, 0, stream>>>(blockv1, blockmask, cbq, c2q, resid,
                                            idx_out, ah, q, W);
    }

    final_kernel<<<MM * DD / 4 / 256, 256, 0, stream>>>(x, resid);
}

// Round 4
// 574.224 us; speedup vs baseline: 2.0485x; 1.1646x over previous
//
#include <hip/hip_runtime.h>

#define BB 8
#define LL 2048
#define DD 512
#define QQ 8
#define KK 2048
#define MM (BB*LL)      // 16384 points

#define BMt 128         // block tile M (2 wr-waves x 64)
#define BNt 128         // block tile N (2 wc-waves x 64)
#define NSTEPS 16       // DD/32
#define NTILES (KK/BNt) // 16
#define MTILES (MM/BMt) // 128

typedef __attribute__((ext_vector_type(8))) short short8;
typedef __attribute__((ext_vector_type(4))) float f32x4;

#define GLDS(src, dst) __builtin_amdgcn_global_load_lds( \
    (const __attribute__((address_space(1))) void*)(src), \
    (__attribute__((address_space(3))) void*)(dst), 16, 0, 0)

__device__ __forceinline__ ushort f2bf(float f) {
    uint u = __float_as_uint(f);
    u += 0x7FFFu + ((u >> 16) & 1u);
    return (ushort)(u >> 16);
}

// ---------------- cb2: fp32 squared norms ----------------
__global__ __launch_bounds__(256) void cb2_kernel(const float* __restrict__ cb,
                                                  float* __restrict__ cb2) {
    int row  = blockIdx.x * 4 + (threadIdx.x >> 6);
    int lane = threadIdx.x & 63;
    const float* r = cb + (size_t)row * DD + lane * 8;
    float4 a = *(const float4*)r;
    float4 b = *(const float4*)(r + 4);
    float s = a.x*a.x + a.y*a.y + a.z*a.z + a.w*a.w
            + b.x*b.x + b.y*b.y + b.z*b.z + b.w*b.w;
    #pragma unroll
    for (int off = 32; off >= 1; off >>= 1) s += __shfl_xor(s, off);
    if (lane == 0) cb2[row] = s;
}

// ---------------- codebook hi-part, wave-contiguous frag order ----------------
// frag idx = (nt*16+ks)*512 + colblk*64 + kk*16 + colr   (nt: 16 tiles of 128 cols)
__global__ __launch_bounds__(256) void bprep_kernel(const float* __restrict__ cbq,
                                                    short8* __restrict__ bh) {
    int r = blockIdx.x * 256 + threadIdx.x;   // 0..131071, write-coalesced
    int colr   = r & 15;
    int kk     = (r >> 4) & 3;
    int colblk = (r >> 6) & 7;
    int ks     = (r >> 9) & 15;
    int nt     = r >> 13;
    const float* src = cbq + (size_t)(nt * 128 + colblk * 16 + colr) * DD + ks * 32 + kk * 8;
    float f[8];
    *(float4*)&f[0] = *(const float4*)src;
    *(float4*)&f[4] = *(const float4*)(src + 4);
    short8 h8;
    #pragma unroll
    for (int j = 0; j < 8; j++) h8[j] = (short)f2bf(f[j]);
    bh[r] = h8;
}

// ---------------- level-0 A prep: resid <- x, ah <- bf16(x) [row][lane] ----------------
// ah layout: ah[row*64 + j] holds bf16 of resid[row][j*8 .. j*8+8)  (identity: j = d/8)
__global__ __launch_bounds__(256) void aprep0_kernel(const float* __restrict__ x,
                                                     float* __restrict__ resid,
                                                     short8* __restrict__ ah) {
    const int wid  = threadIdx.x >> 6;
    const int lane = threadIdx.x & 63;
    const int row  = blockIdx.x * 4 + wid;
    const float* src = x + (size_t)row * DD + lane * 8;
    float4 v0 = *(const float4*)src;
    float4 v1 = *(const float4*)(src + 4);
    float* dst = resid + (size_t)row * DD + lane * 8;
    *(float4*)dst       = v0;
    *(float4*)(dst + 4) = v1;
    short8 h;
    h[0] = (short)f2bf(v0.x); h[1] = (short)f2bf(v0.y);
    h[2] = (short)f2bf(v0.z); h[3] = (short)f2bf(v0.w);
    h[4] = (short)f2bf(v1.x); h[5] = (short)f2bf(v1.y);
    h[6] = (short)f2bf(v1.z); h[7] = (short)f2bf(v1.w);
    ah[(size_t)row * 64 + lane] = h;
}

// ---------------- 1-term bf16 GEMM + per-tile (v1, candidate bitmask) ----------------
// Operand-swapped MFMA: lane holds 16 cols of ONE row per m-frag.
// ah is [row][j]: STAGE uses per-lane GLOBAL src (legal) + linear LDS dest;
// A frag read index becomes wr*256 + m*64 + (l15<<2) + l4 (same data per lane).
// Epilogue: phase A tile-min, one barrier, phase B writes v1 + 64-bit mask word
// per wc-half directly to global (no phase C, no second barrier).
__global__ __launch_bounds__(256, 4) void gemm_argmin_kernel(
    const short8* __restrict__ ah,
    const short8* __restrict__ bh,
    const float*  __restrict__ cb2q,
    float*        __restrict__ blockv1,    // [NTILES][MM]
    uint4*        __restrict__ blockmask,  // [NTILES][MM] (two 64-bit halves)
    float W)
{
    __shared__ short8 smem[2][1024];   // 32 KB: per buf A [0..512), B [512..1024)

    const int id   = blockIdx.x;
    const int xcd  = id & 7;
    const int slot = id >> 3;            // 0..255
    const int nt   = slot & 15;
    const int mt   = xcd * 16 + (slot >> 4);

    const int t    = threadIdx.x;
    const int wid  = t >> 6;
    const int lane = t & 63;
    const int wr   = wid >> 1, wc = wid & 1;
    const int l15  = lane & 15, l4 = lane >> 4;

    // acc[n][m]: codebook-col frag n, point-row frag m (operand-swapped MFMA)
    f32x4 acc[4][4];
    #pragma unroll
    for (int n = 0; n < 4; n++)
        #pragma unroll
        for (int m = 0; m < 4; m++) acc[n][m] = (f32x4){0.f, 0.f, 0.f, 0.f};

    const char* aSrc = (const char*)ah + (size_t)mt * 131072;   // 128 rows x 1 KB
    const char* bSrc = (const char*)bh + (size_t)nt * 131072;

    const int rlo = lane >> 2;            // row-in-16 for A staging
    const int kb  = (lane & 3) * 16;      // kk byte offset

    auto STAGE = [&](int ks, int buf) {
        char* dst = (char*)&smem[buf][0];
        const char* bs = bSrc + (size_t)ks * 8192;
        #pragma unroll
        for (int j = 0; j < 2; j++) {
            int c = wid * 2 + j;
            GLDS(aSrc + (size_t)(c * 16 + rlo) * 1024 + ks * 64 + kb,
                 dst + c * 1024 + lane * 16);
            GLDS(bs + c * 1024 + lane * 16, dst + 8192 + c * 1024);
        }
    };

    int buf = 0;
    STAGE(0, 0);

    for (int ks = 0; ks < NSTEPS; ks++) {
        __syncthreads();
        if (ks < NSTEPS - 1) STAGE(ks + 1, buf ^ 1);

        short8 af[4], bf[4];
        #pragma unroll
        for (int m = 0; m < 4; m++)
            af[m] = smem[buf][wr * 256 + m * 64 + (l15 << 2) + l4];
        #pragma unroll
        for (int n = 0; n < 4; n++)
            bf[n] = smem[buf][512 + wc * 256 + n * 64 + lane];

        #pragma unroll
        for (int n = 0; n < 4; n++)
            #pragma unroll
            for (int m = 0; m < 4; m++)
                acc[n][m] = __builtin_amdgcn_mfma_f32_16x16x32_bf16(bf[n], af[m], acc[n][m], 0, 0, 0);

        buf ^= 1;
    }

    // ---- epilogue ----
    // acc[n][m][r]: row = wr*64 + m*16 + l15 ; col = wc*64 + n*16 + l4*4 + r
    // Last K-step read smem[1]; halfmin lives in smem[0] -> no barrier before phase A.
    float* halfmin = (float*)&smem[0][0];   // [128][2]

    f32x4 c2v[4];
    #pragma unroll
    for (int n = 0; n < 4; n++)
        c2v[n] = *(const f32x4*)&cb2q[nt * 128 + wc * 64 + n * 16 + (l4 << 2)];

    // phase A: per-row per-wc-half min
    #pragma unroll
    for (int m = 0; m < 4; m++) {
        float v1 = 3.4e38f;
        #pragma unroll
        for (int n = 0; n < 4; n++)
            #pragma unroll
            for (int r = 0; r < 4; r++)
                v1 = fminf(v1, fmaf(-2.f, acc[n][m][r], c2v[n][r]));
        v1 = fminf(v1, __shfl_xor(v1, 16));
        v1 = fminf(v1, __shfl_xor(v1, 32));
        if (l4 == 0) halfmin[((wr << 6) + (m << 4) + l15) * 2 + wc] = v1;
    }
    __syncthreads();

    // phase B: candidate mask at v1_tile + W; write v1 + own 64-bit half directly
    #pragma unroll
    for (int m = 0; m < 4; m++) {
        int rowl = (wr << 6) + (m << 4) + l15;
        float vt = fminf(halfmin[rowl * 2], halfmin[rowl * 2 + 1]);
        float thrm = vt + W;
        uint blo = 0, bhi = 0;
        #pragma unroll
        for (int n = 0; n < 4; n++)
            #pragma unroll
            for (int r = 0; r < 4; r++) {
                float d = fmaf(-2.f, acc[n][m][r], c2v[n][r]);
                int bit = n * 16 + (l4 << 2) + r;
                if (d < thrm) { if (bit < 32) blo |= 1u << bit; else bhi |= 1u << (bit - 32); }
            }
        blo |= __shfl_xor(blo, 16); bhi |= __shfl_xor(bhi, 16);
        blo |= __shfl_xor(blo, 32); bhi |= __shfl_xor(bhi, 32);
        if (l4 == 0) {
            size_t o = (size_t)nt * MM + mt * BMt + rowl;
            ((uint2*)blockmask)[o * 2 + wc] = make_uint2(blo, bhi);
            if (wc == 0) blockv1[o] = vt;
        }
    }
}

// ---------------- combine + exact refine + update: ONE WAVE PER ROW, no barriers ----
// Candidate extraction straight from the 128-bit masks (wave-uniform scalar loops);
// eval 4-wide via 16-lane groups; broadcast-merge leaves identical (be,bk) in all
// lanes -> no winner handoff. 4 independent waves/block -> 32 rows in flight/CU.
__global__ __launch_bounds__(256) void crru_kernel(
    const float*  __restrict__ blockv1,
    const uint4*  __restrict__ blockmask,
    const float*  __restrict__ cbq,
    const float*  __restrict__ cb2q,
    float*        __restrict__ resid,
    float*        __restrict__ idx_out,
    short8*       __restrict__ ah,
    int q, float W)
{
    __shared__ float rs[4][DD];          // 8 KB: per-wave resid row
    const int wid  = threadIdx.x >> 6;
    const int lane = threadIdx.x & 63;
    const int row  = blockIdx.x * 4 + wid;
    const int grp  = lane >> 4, gl = lane & 15;

    // classification loads (lanes 0..15), issued early
    float v1 = 3.4e38f;
    uint4 mk = make_uint4(0, 0, 0, 0);
    if (lane < NTILES) {
        size_t o = (size_t)lane * MM + row;
        v1 = blockv1[o];
        mk = blockmask[o];
    }

    // stage resid row into LDS (same-wave RAW: compiler inserts lgkmcnt)
    float* rrow = resid + (size_t)row * DD + lane * 8;
    float4 r0 = *(const float4*)rrow;
    float4 r1 = *(const float4*)(rrow + 4);
    *(float4*)&rs[wid][lane * 8]     = r0;
    *(float4*)&rs[wid][lane * 8 + 4] = r1;

    float g1 = v1;
    #pragma unroll
    for (int off = 32; off >= 1; off >>= 1) g1 = fminf(g1, __shfl_xor(g1, off));
    const float thr = g1 + W;

    unsigned long long act = __ballot((lane < NTILES) && (v1 < thr));

    float be = 3.4e38f; int bk = 0x7FFFFFFF;
    const float* rsw = rs[wid];

    auto eval4 = [&](int k0, int k1, int k2, int k3) {
        int kg = (grp == 0) ? k0 : (grp == 1) ? k1 : (grp == 2) ? k2 : k3;
        float d = 0.f;
        if (kg >= 0) {
            const float* cp = cbq + (size_t)kg * DD + gl * 32;
            const float* rp = rsw + gl * 32;
            #pragma unroll
            for (int j = 0; j < 8; j++) {
                float4 c = *(const float4*)(cp + j * 4);
                float4 r = *(const float4*)(rp + j * 4);
                d = fmaf(r.x, c.x, d); d = fmaf(r.y, c.y, d);
                d = fmaf(r.z, c.z, d); d = fmaf(r.w, c.w, d);
            }
        }
        #pragma unroll
        for (int off = 8; off >= 1; off >>= 1) d += __shfl_xor(d, off);
        #pragma unroll
        for (int g = 0; g < 4; g++) {
            float dg = __shfl(d, g * 16);
            int kg2 = (g == 0) ? k0 : (g == 1) ? k1 : (g == 2) ? k2 : k3;
            if (kg2 >= 0) {
                float e = fmaf(-2.f, dg, cb2q[kg2]);
                if (e < be || (e == be && kg2 < bk)) { be = e; bk = kg2; }
            }
        }
    };

    while (act) {
        int tile = __ffsll(act) - 1; act &= act - 1;
        // broadcast this tile's 128-bit mask (wave-uniform afterwards)
        uint m0 = __shfl((int)mk.x, tile), m1 = __shfl((int)mk.y, tile);
        uint m2 = __shfl((int)mk.z, tile), m3 = __shfl((int)mk.w, tile);
        unsigned long long lo = ((unsigned long long)m1 << 32) | m0;
        unsigned long long hi = ((unsigned long long)m3 << 32) | m2;
        int base = tile * 128;
        while (lo | hi) {
            int c0 = -1, c1 = -1, c2 = -1, c3 = -1;
            #define POP1(dst) \
                if (lo) { int b = __ffsll(lo) - 1; lo &= lo - 1; dst = base + b; } \
                else if (hi) { int b = __ffsll(hi) - 1; hi &= hi - 1; dst = base + 64 + b; }
            POP1(c0) POP1(c1) POP1(c2) POP1(c3)
            #undef POP1
            eval4(c0, c1, c2, c3);
        }
    }
    const int winner = bk;   // identical in all lanes

    if (lane == 0) {
        int b = row >> 11, l = row & (LL - 1);
        idx_out[((size_t)b * QQ + q) * LL + l] = (float)winner;
    }

    const float* cw = cbq + (size_t)winner * DD + lane * 8;
    float4 c0 = *(const float4*)cw;
    float4 c1 = *(const float4*)(cw + 4);
    float4 n0 = make_float4(r0.x - c0.x, r0.y - c0.y, r0.z - c0.z, r0.w - c0.w);
    float4 n1 = make_float4(r1.x - c1.x, r1.y - c1.y, r1.z - c1.z, r1.w - c1.w);
    *(float4*)rrow       = n0;
    *(float4*)(rrow + 4) = n1;

    if (q < QQ - 1) {
        short8 h;
        h[0] = (short)f2bf(n0.x); h[1] = (short)f2bf(n0.y);
        h[2] = (short)f2bf(n0.z); h[3] = (short)f2bf(n0.w);
        h[4] = (short)f2bf(n1.x); h[5] = (short)f2bf(n1.y);
        h[6] = (short)f2bf(n1.z); h[7] = (short)f2bf(n1.w);
        ah[(size_t)row * 64 + lane] = h;   // coalesced 1 KB/row
    }
}

// ---------------- quantized = x - r_final ----------------
__global__ __launch_bounds__(256) void final_kernel(const float* __restrict__ x,
                                                    float* __restrict__ qout) {
    size_t i = (size_t)blockIdx.x * 256 + threadIdx.x;
    float4 xv = ((const float4*)x)[i];
    float4 rv = ((float4*)qout)[i];
    ((float4*)qout)[i] = make_float4(xv.x - rv.x, xv.y - rv.y, xv.z - rv.z, xv.w - rv.w);
}

extern "C" void kernel_launch(void* const* d_in, const int* in_sizes, int n_in,
                              void* d_out, int out_size, void* d_ws, size_t ws_size,
                              hipStream_t stream) {
    (void)in_sizes; (void)n_in; (void)out_size; (void)ws_size;
    const float* x  = (const float*)d_in[0];
    const float* cb = (const float*)d_in[1];
    float* out = (float*)d_out;

    float* idx_out = out;                           // BB*QQ*LL floats
    float* resid   = out + (size_t)BB * QQ * LL;    // doubles as quantized output

    char* w = (char*)d_ws;
    float*  cb2       = (float*)(w);                 // 64 KB
    float*  blockv1   = (float*)(w + 0x10000);       // 1 MB  -> ends 0x110000
    uint4*  blockmask = (uint4*)(w + 0x110000);      // 4 MB  -> ends 0x510000
    short8* ah        = (short8*)(w + 0x510000);     // 16 MB -> ends 0x1510000
    short8* bh        = (short8*)(w + 0x1510000);    // 2 MB  -> ends 0x1710000 (~24 MB)

    cb2_kernel<<<QQ * KK / 4, 256, 0, stream>>>(cb, cb2);
    aprep0_kernel<<<MM / 4, 256, 0, stream>>>(x, resid, ah);

    for (int q = 0; q < QQ; q++) {
        const float* cbq = cb + (size_t)q * KK * DD;
        const float* c2q = cb2 + (size_t)q * KK;
        const float W = 2.0f + 0.3f * q;   // proven coverage window (R7-R9)

        bprep_kernel<<<KK * DD / 8 / 256, 256, 0, stream>>>(cbq, bh);

        gemm_argmin_kernel<<<NTILES * MTILES, 256, 0, stream>>>(ah, bh, c2q,
                                                                blockv1, blockmask, W);

        crru_kernel<<<MM / 4, 256, 0, stream>>>(blockv1, blockmask, cbq, c2q, resid,
                                                idx_out, ah, q, W);
    }

    final_kernel<<<MM * DD / 4 / 256, 256, 0, stream>>>(x, resid);
}